// Round 13
// baseline (242.407 us; speedup 1.0000x reference)
//
#include <hip/hip_runtime.h>
#include <hip/hip_bf16.h>
#include <math.h>

#define NN 10000

typedef __attribute__((ext_vector_type(4))) float f32x4;
typedef __attribute__((ext_vector_type(8))) short short8v;

__device__ __forceinline__ short f2bf(float f) {
  union { float f; unsigned u; } v; v.f = f;
  unsigned u = v.u + 0x7FFFu + ((v.u >> 16) & 1u);  // RNE
  return (short)(u >> 16);
}
__device__ __forceinline__ float bf2f(unsigned short h) {
  union { unsigned u; float f; } v; v.u = ((unsigned)h) << 16;
  return v.f;
}
__device__ __forceinline__ float artanh_(float xx) {
  xx = fminf(fmaxf(xx, -1.f + 1e-7f), 1.f - 1e-7f);
  return atanhf(xx);
}
__device__ __forceinline__ void proj16(float* v) {
  float s = 0.f;
#pragma unroll
  for (int i = 0; i < 16; ++i) s += v[i] * v[i];
  float n = fmaxf(sqrtf(s), 1e-15f);
  const float mxn = 1.0f - 4e-3f;
  if (n > mxn) {
    float sc = mxn / n;
#pragma unroll
    for (int i = 0; i < 16; ++i) v[i] *= sc;
  }
}
__device__ __forceinline__ short8v cvt8(const float4& u, const float4& w) {
  union { __hip_bfloat162 h; unsigned u32; } c0, c1, c2, c3;
  c0.h = __float22bfloat162_rn(make_float2(u.x, u.y));
  c1.h = __float22bfloat162_rn(make_float2(u.z, u.w));
  c2.h = __float22bfloat162_rn(make_float2(w.x, w.y));
  c3.h = __float22bfloat162_rn(make_float2(w.z, w.w));
  union { unsigned v[4]; short8v s; } r;
  r.v[0] = c0.u32; r.v[1] = c1.u32; r.v[2] = c2.u32; r.v[3] = c3.u32;
  return r.s;
}

// ---------------- K1: fused attn1+attn2 — rhs stays in LDS; partials for a[f,t] and M[f,s] ----------------
__global__ __launch_bounds__(192) void k_attn12(
    const float* __restrict__ x,
    const float* __restrict__ U1a, const float* __restrict__ U3a, const float* __restrict__ U2a,
    const float* __restrict__ U1b, const float* __restrict__ U3b, const float* __restrict__ U2b,
    float* __restrict__ partAa, float* __restrict__ partAb,
    float* __restrict__ partMa, float* __restrict__ partMb,
    unsigned short* __restrict__ PB) {
  __shared__ float xs[16 * 193];
  __shared__ float rsA[16][13], rsB[16][13];
  int tid = threadIdx.x;
  int f_ = tid / 12, t_ = tid - f_ * 12;   // (f, t) for partA and (f, s) for partM
  int s_ = tid >> 4, nl_ = tid & 15;       // (n-local, s) for rhs
  // zero PB pad: frag-step 312, shorts [256,512) of each of its 12 frags (k >= 10000)
  if (blockIdx.x == 79) {
    for (int i = tid; i < 3072; i += 192) {
      int tt = i >> 8, q = i & 255;
      PB[(size_t)(312 * 12 + tt) * 512 + 256 + q] = 0;
    }
  }
  float paa = 0.f, pab = 0.f, ma = 0.f, mb = 0.f;
  for (int tb = blockIdx.x; tb < 625; tb += 160) {
    int n0 = tb * 16;
    for (int i = tid; i < 16 * 192; i += 192) {
      int a = i / 192, j = i - a * 192;
      xs[a * 193 + j] = x[(size_t)(n0 + a) * 192 + j];
    }
    __syncthreads();
    // rhs[n,s] for this tile -> LDS
    {
      float ra = 0.f, rb = 0.f;
#pragma unroll
      for (int f = 0; f < 16; ++f) {
        float xv = xs[nl_ * 193 + f * 12 + s_];
        ra += xv * U3a[f];
        rb += xv * U3b[f];
      }
      rsA[nl_][s_] = ra;
      rsB[nl_][s_] = rb;
    }
    // partA[f,t] += sum_nl x[nl,f,t] * U1[n0+nl]
#pragma unroll
    for (int nl = 0; nl < 16; ++nl) {
      float xv = xs[nl * 193 + f_ * 12 + t_];
      paa += xv * U1a[n0 + nl];
      pab += xv * U1b[n0 + nl];
    }
    __syncthreads();
    // partM[f,s] += sum_nl U2[f, n0+nl] * rhs[nl, s]
#pragma unroll
    for (int nl = 0; nl < 16; ++nl) {
      float u2a = U2a[(size_t)f_ * NN + n0 + nl];
      float u2b = U2b[(size_t)f_ * NN + n0 + nl];
      ma += u2a * rsA[nl][t_];
      mb += u2b * rsB[nl][t_];
    }
    __syncthreads();
  }
  partAa[blockIdx.x * 192 + tid] = paa;
  partAb[blockIdx.x * 192 + tid] = pab;
  partMa[blockIdx.x * 192 + tid] = ma;
  partMb[blockIdx.x * 192 + tid] = mb;
}

// ---------------- K3: reduce partials, product, E, softmax -> tA (both) ----------------
__global__ __launch_bounds__(192) void k_attn3(
    const float* __restrict__ partAa, const float* __restrict__ partAb,
    const float* __restrict__ partMa, const float* __restrict__ partMb,
    const float* __restrict__ beA, const float* __restrict__ VeA,
    const float* __restrict__ beB, const float* __restrict__ VeB,
    float* __restrict__ tAa, float* __restrict__ tAb) {
  __shared__ float aa[192], ab[192], Ma[192], Mb[192];
  __shared__ float spA[144], spB[144], EA[144], EB[144];
  int tid = threadIdx.x;
  float s1 = 0.f, s2 = 0.f, s3 = 0.f, s4 = 0.f;
  for (int b = 0; b < 160; ++b) {
    s1 += partAa[b * 192 + tid]; s2 += partAb[b * 192 + tid];
    s3 += partMa[b * 192 + tid]; s4 += partMb[b * 192 + tid];
  }
  aa[tid] = s1; ab[tid] = s2; Ma[tid] = s3; Mb[tid] = s4;
  __syncthreads();
  if (tid < 144) {
    int j = tid / 12, s = tid - j * 12;
    float pa = 0.f, pb = 0.f;
#pragma unroll
    for (int f = 0; f < 16; ++f) {
      pa += aa[f * 12 + j] * Ma[f * 12 + s];
      pb += ab[f * 12 + j] * Mb[f * 12 + s];
    }
    spA[tid] = 1.f / (1.f + expf(-(pa + beA[tid])));
    spB[tid] = 1.f / (1.f + expf(-(pb + beB[tid])));
  }
  __syncthreads();
  if (tid < 144) {
    int i = tid / 12, s = tid - i * 12;
    float ea = 0.f, eb = 0.f;
#pragma unroll
    for (int j = 0; j < 12; ++j) {
      ea += VeA[i * 12 + j] * spA[j * 12 + s];
      eb += VeB[i * 12 + j] * spB[j * 12 + s];
    }
    EA[tid] = ea; EB[tid] = eb;
  }
  __syncthreads();
  if (tid < 144) {
    int s = tid % 12;
    float ma = -1e30f, mb = -1e30f;
#pragma unroll
    for (int k = 0; k < 12; ++k) { ma = fmaxf(ma, EA[k * 12 + s]); mb = fmaxf(mb, EB[k * 12 + s]); }
    float da = 0.f, db = 0.f;
#pragma unroll
    for (int k = 0; k < 12; ++k) { da += expf(EA[k * 12 + s] - ma); db += expf(EB[k * 12 + s] - mb); }
    tAa[tid] = expf(EA[tid] - ma) / da;
    tAb[tid] = expf(EB[tid] - mb) / db;
  }
}

// ---------------- K4: split-halves — threads 0-191 branch-b (outF), 192-383 branch-a (PB) ----------------
__global__ __launch_bounds__(384) void k_node(
    const float* __restrict__ x,
    const float* __restrict__ tAa_g, const float* __restrict__ tAb_g,
    const float* __restrict__ w1g, const float* __restrict__ b1g,
    const float* __restrict__ w2g, const float* __restrict__ b2g,
    const float* __restrict__ hwg, const float* __restrict__ hbg,
    float* __restrict__ outF, unsigned short* __restrict__ PB) {
  __shared__ float xs[16 * 193], tbA[16 * 193], tbB[16 * 193];
  __shared__ float tAa[144], tAb[144], w1[768], w2[768];
  __shared__ float cb1[16], cb2[16], hw[256], hbr[16];
  int tid = threadIdx.x;
  int half = tid / 192, lt = tid - half * 192;  // half 0: branch b, half 1: branch a
  int nl = lt & 15, tt = lt >> 4;
  int n0 = blockIdx.x * 16;
  for (int i = tid; i < 144; i += 384) { tAa[i] = tAa_g[i]; tAb[i] = tAb_g[i]; }
  for (int i = tid; i < 768; i += 384) { w1[i] = w1g[i]; w2[i] = w2g[i]; }
  for (int i = tid; i < 256; i += 384) hw[i] = hwg[i];
  if (tid < 16) { cb1[tid] = b1g[tid]; cb2[tid] = b2g[tid]; hbr[tid] = hbg[tid]; }
  for (int i = tid; i < 16 * 192; i += 384) {
    int a = i / 192, j = i - a * 192;
    xs[a * 193 + j] = x[(size_t)(n0 + a) * 192 + j];
  }
  __syncthreads();

  // tbuf phase: each half computes its branch's x_tat
  float* tb = half ? tbA : tbB;
  const float* tA = half ? tAa : tAb;
#pragma unroll
  for (int f = 0; f < 16; ++f) {
    float v = 0.f;
#pragma unroll
    for (int s = 0; s < 12; ++s) v += xs[nl * 193 + f * 12 + s] * tA[s * 12 + tt];
    tb[nl * 193 + f * 12 + tt] = v;
  }
  __syncthreads();

  // conv phase
  const float* wv = half ? w1 : w2;
  const float* cbv = half ? cb1 : cb2;
  float z[16];
#pragma unroll
  for (int o = 0; o < 16; ++o) z[o] = cbv[o];
#pragma unroll
  for (int k = 0; k < 3; ++k) {
    int t2 = tt + k - 1;
    if (t2 >= 0 && t2 < 12) {
#pragma unroll
      for (int i = 0; i < 16; ++i) {
        float xv = tb[nl * 193 + i * 12 + t2];
#pragma unroll
        for (int o = 0; o < 16; ++o) z[o] += xv * wv[o * 48 + i * 3 + k];
      }
    }
  }

  if (half == 0) {
    // branch b -> final_output
    float* op = outF + (size_t)tt * (NN * 16) + (size_t)(n0 + nl) * 16;
#pragma unroll
    for (int o = 0; o < 16; ++o) op[o] = z[o];
    return;
  }

  // branch a -> hyperbolic chain -> PB
  float nz = 0.f;
#pragma unroll
  for (int i = 0; i < 16; ++i) nz += z[i] * z[i];
  nz = fmaxf(sqrtf(nz), 1e-15f);
  float sc0 = tanhf(nz) / nz;
#pragma unroll
  for (int i = 0; i < 16; ++i) z[i] *= sc0;
  proj16(z);
  float xn = 0.f;
#pragma unroll
  for (int i = 0; i < 16; ++i) xn += z[i] * z[i];
  xn = fmaxf(sqrtf(xn), 1e-15f);
  float mx[16];
#pragma unroll
  for (int d = 0; d < 16; ++d) {
    float v = 0.f;
#pragma unroll
    for (int f = 0; f < 16; ++f) v += z[f] * hw[d * 16 + f];
    mx[d] = v;
  }
  float mxr = 0.f;
#pragma unroll
  for (int d = 0; d < 16; ++d) mxr += mx[d] * mx[d];
  mxr = sqrtf(mxr);
  float mxn = fmaxf(mxr, 1e-15f);
  float rs = tanhf(mxn / xn * artanh_(xn)) / mxn;
  if (mxr == 0.f) rs = 0.f;
#pragma unroll
  for (int d = 0; d < 16; ++d) mx[d] *= rs;
  proj16(mx);
  float hb[16];
  float bn = 0.f;
#pragma unroll
  for (int i = 0; i < 16; ++i) { hb[i] = hbr[i]; bn += hb[i] * hb[i]; }
  bn = fmaxf(sqrtf(bn), 1e-15f);
  float sb = tanhf(bn) / bn;
#pragma unroll
  for (int i = 0; i < 16; ++i) hb[i] *= sb;
  proj16(hb);
  float x2 = 0.f, y2 = 0.f, xy = 0.f;
#pragma unroll
  for (int i = 0; i < 16; ++i) { x2 += mx[i] * mx[i]; y2 += hb[i] * hb[i]; xy += mx[i] * hb[i]; }
  float ca = 1.f + 2.f * xy + y2;
  float cbf = 1.f - x2;
  float den = fmaxf(1.f + 2.f * xy + x2 * y2, 1e-15f);
#pragma unroll
  for (int i = 0; i < 16; ++i) mx[i] = (ca * mx[i] + cbf * hb[i]) / den;
  proj16(mx);
  float pn = 0.f;
#pragma unroll
  for (int i = 0; i < 16; ++i) pn += mx[i] * mx[i];
  pn = fmaxf(sqrtf(pn), 1e-15f);
  float sl = artanh_(pn) / pn;
  {
    int nn2 = n0 + nl;
    int s = nn2 >> 5, c = nn2 & 31;
    unsigned short* pp = PB + (size_t)(s * 12 + tt) * 512 + (c >> 3) * 128 + (c & 7);
#pragma unroll
    for (int d = 0; d < 16; ++d)
      pp[d * 8] = (unsigned short)f2bf(mx[d] * sl);
  }
}

// ---------------- K5: sup = adj @ xt — BM=256, 8 waves, all-3-deep LDS, ONE barrier/step (R12) ----------------
__global__ __launch_bounds__(512) void k_gemm(
    const float* __restrict__ adj, const unsigned short* __restrict__ PB,
    unsigned short* __restrict__ partC, int S) {
  extern __shared__ char smem[];  // A: 3 x 32768 at p*32768 ; B: 3 x 12288 at 98304+p*12288
  int tid = threadIdx.x;
  int w = tid >> 6, lane = tid & 63;
  int bc = blockIdx.x / 40;
  int rt = blockIdx.x - bc * 40;
  int t0 = bc * S, t1 = min(313, t0 + S);
  int ns = t1 - t0;
  int r0 = lane & 15, kq = lane >> 4;
  int R0w = rt * 256 + w * 32;

  int aoffF = (((lane & 7) * 16) ^ ((lane >> 3) << 4)) >> 2;
  int arow[4];
#pragma unroll
  for (int i = 0; i < 4; ++i) arow[i] = min(R0w + i * 8 + (lane >> 3), NN - 1);

  int bc0 = w;
  int bc1 = (w < 4) ? (8 + w) : w;

  f32x4 acc0[12], acc1[12];
  f32x4 zz = {0.f, 0.f, 0.f, 0.f};
#pragma unroll
  for (int j = 0; j < 12; ++j) { acc0[j] = zz; acc1[j] = zz; }

  auto STAGE = [&](int p, int t) {  // exactly 6 gll per wave, all width-16
    char* Bdst = smem + 98304 + p * 12288;
    const char* Bsrc = (const char*)PB + (size_t)t * 12288;
    __builtin_amdgcn_global_load_lds((const void*)(Bsrc + bc0 * 1024 + lane * 16),
                                     (void*)(Bdst + bc0 * 1024 + lane * 16), 16, 0, 0);
    __builtin_amdgcn_global_load_lds((const void*)(Bsrc + bc1 * 1024 + lane * 16),
                                     (void*)(Bdst + bc1 * 1024 + lane * 16), 16, 0, 0);
    char* Adst = smem + p * 32768 + (w * 32) * 128;
#pragma unroll
    for (int i = 0; i < 4; ++i) {
      int fo = t * 32 + aoffF;
      if (fo >= NN) fo = 0;
      __builtin_amdgcn_global_load_lds((const void*)(adj + (size_t)arow[i] * NN + fo),
                                       (void*)(Adst + i * 1024 + lane * 16), 16, 0, 0);
    }
  };

  int xr = (r0 & 7) << 4;
  auto MM = [&](int p) {
    const char* Ab = smem + p * 32768 + (w * 32) * 128;
    const char* Bb = smem + 98304 + p * 12288;
    float4 a00 = *(const float4*)(Ab + r0 * 128 + ((kq * 32) ^ xr));
    float4 a01 = *(const float4*)(Ab + r0 * 128 + ((kq * 32 + 16) ^ xr));
    float4 a10 = *(const float4*)(Ab + (r0 + 16) * 128 + ((kq * 32) ^ xr));
    float4 a11 = *(const float4*)(Ab + (r0 + 16) * 128 + ((kq * 32 + 16) ^ xr));
    short8v fa0 = cvt8(a00, a01);
    short8v fa1 = cvt8(a10, a11);
#pragma unroll
    for (int j = 0; j < 12; ++j) {
      short8v b = *(const short8v*)(Bb + j * 1024 + lane * 16);
      acc0[j] = __builtin_amdgcn_mfma_f32_16x16x32_bf16(fa0, b, acc0[j], 0, 0, 0);
      acc1[j] = __builtin_amdgcn_mfma_f32_16x16x32_bf16(fa1, b, acc1[j], 0, 0, 0);
    }
  };

  STAGE(0, t0);
  if (ns > 1) STAGE(1, t0 + 1);
  if (ns > 1) asm volatile("s_waitcnt vmcnt(6)" ::: "memory");
  else        asm volatile("s_waitcnt vmcnt(0)" ::: "memory");
  __builtin_amdgcn_sched_barrier(0);
  __builtin_amdgcn_s_barrier();
  __builtin_amdgcn_sched_barrier(0);

  for (int i = 0; i < ns; ++i) {
    if (i + 2 < ns) STAGE((i + 2) % 3, t0 + i + 2);
    MM(i % 3);
    asm volatile("s_waitcnt lgkmcnt(0)" ::: "memory");
    if (i + 1 < ns) {
      if (i + 2 < ns) asm volatile("s_waitcnt vmcnt(6)" ::: "memory");
      else            asm volatile("s_waitcnt vmcnt(0)" ::: "memory");
      __builtin_amdgcn_sched_barrier(0);
      __builtin_amdgcn_s_barrier();
      __builtin_amdgcn_sched_barrier(0);
    }
  }

  size_t cbase = (size_t)bc * ((size_t)NN * 192);
  int drow = kq * 4;
#pragma unroll
  for (int j = 0; j < 12; ++j) {
#pragma unroll
    for (int r = 0; r < 4; ++r) {
      int rw0 = R0w + drow + r;
      int rw1 = R0w + 16 + drow + r;
      if (rw0 < NN)
        partC[cbase + (size_t)rw0 * 192 + j * 16 + r0] = (unsigned short)f2bf(acc0[j][r]);
      if (rw1 < NN)
        partC[cbase + (size_t)rw1 * 192 + j * 16 + r0] = (unsigned short)f2bf(acc1[j][r]);
    }
  }
}

// ---------------- K6: reduce partials + hyperbolic epilogue -> h (coalesced via LDS transpose) ----------------
__global__ __launch_bounds__(192) void k_epi(const unsigned short* __restrict__ partC,
                                             float* __restrict__ outH, int NC) {
  __shared__ float tr[16][196];
  int tid = threadIdx.x;
  int nl = tid >> 4 == 12 ? 0 : 0;  // placeholder (unused)
  (void)nl;
  int node = tid / 12, t = tid - node * 12;  // 16 nodes x 12 t
  int n = blockIdx.x * 16 + node;
  float sup[16];
#pragma unroll
  for (int d = 0; d < 16; ++d) sup[d] = 0.f;
  for (int c = 0; c < NC; ++c) {
    const short8v* p8 = (const short8v*)(partC + (size_t)c * (NN * 192) + (size_t)n * 192 + t * 16);
    short8v lo = p8[0], hi = p8[1];
#pragma unroll
    for (int d = 0; d < 8; ++d) sup[d] += bf2f((unsigned short)lo[d]);
#pragma unroll
    for (int d = 0; d < 8; ++d) sup[8 + d] += bf2f((unsigned short)hi[d]);
  }
  // agg = proj(expmap0(sup))
  float nn_ = 0.f;
#pragma unroll
  for (int d = 0; d < 16; ++d) nn_ += sup[d] * sup[d];
  nn_ = fmaxf(sqrtf(nn_), 1e-15f);
  float s0 = tanhf(nn_) / nn_;
#pragma unroll
  for (int d = 0; d < 16; ++d) sup[d] *= s0;
  proj16(sup);
  // relu(logmap0(agg))
  float pn = 0.f;
#pragma unroll
  for (int d = 0; d < 16; ++d) pn += sup[d] * sup[d];
  pn = fmaxf(sqrtf(pn), 1e-15f);
  float sl = artanh_(pn) / pn;
#pragma unroll
  for (int d = 0; d < 16; ++d) sup[d] = fmaxf(sup[d] * sl, 0.f);
  // proj(expmap0(...))
  float un = 0.f;
#pragma unroll
  for (int d = 0; d < 16; ++d) un += sup[d] * sup[d];
  un = fmaxf(sqrtf(un), 1e-15f);
  float se = tanhf(un) / un;
#pragma unroll
  for (int d = 0; d < 16; ++d) sup[d] *= se;
  proj16(sup);
  // stage h[node][d][t] into LDS, then write coalesced 16-float chunks
#pragma unroll
  for (int d = 0; d < 16; ++d) tr[node][d * 12 + t] = sup[d];
  __syncthreads();
  int wn = tid >> 4, wc = tid & 15;  // 12 threads... (16 nodes x 12 chunks): remap
  wn = tid / 12; wc = tid - wn * 12;
  float* hp = outH + (size_t)(blockIdx.x * 16 + wn) * 192 + wc * 16;
#pragma unroll
  for (int i = 0; i < 16; ++i) hp[i] = tr[wn][wc * 16 + i];
}

extern "C" void kernel_launch(void* const* d_in, const int* in_sizes, int n_in,
                              void* d_out, int out_size, void* d_ws, size_t ws_size,
                              hipStream_t stream) {
  const float* x   = (const float*)d_in[0];
  const float* adj = (const float*)d_in[1];
  const float* U1a = (const float*)d_in[2];
  const float* U2a = (const float*)d_in[3];
  const float* U3a = (const float*)d_in[4];
  const float* bea = (const float*)d_in[5];
  const float* Vea = (const float*)d_in[6];
  const float* U1b = (const float*)d_in[7];
  const float* U2b = (const float*)d_in[8];
  const float* U3b = (const float*)d_in[9];
  const float* beb = (const float*)d_in[10];
  const float* Veb = (const float*)d_in[11];
  const float* w1  = (const float*)d_in[12];
  const float* b1  = (const float*)d_in[13];
  const float* w2  = (const float*)d_in[14];
  const float* b2  = (const float*)d_in[15];
  const float* hw  = (const float*)d_in[16];
  const float* hb  = (const float*)d_in[17];
  float* outF = (float*)d_out;
  float* outH = (float*)d_out + 1920000;

  char* ws = (char*)d_ws;
  size_t off = 0;
  auto alloc = [&](size_t bytes) {
    char* p = ws + off;
    off = (off + bytes + 255) & ~(size_t)255;
    return p;
  };
  float* partAa = (float*)alloc(160 * 192 * 4);
  float* partAb = (float*)alloc(160 * 192 * 4);
  float* partMa = (float*)alloc(160 * 192 * 4);
  float* partMb = (float*)alloc(160 * 192 * 4);
  float* tAa    = (float*)alloc(144 * 4);
  float* tAb    = (float*)alloc(144 * 4);
  unsigned short* PB = (unsigned short*)alloc((size_t)314 * 6144 * 2);
  const int NC = 6;                 // 40 x 6 = 240 blocks -> single scheduling round
  unsigned short* partC = (unsigned short*)alloc((size_t)NC * NN * 192 * 2);
  (void)ws_size;
  int S = (313 + NC - 1) / NC;      // 53

  (void)hipFuncSetAttribute((const void*)k_gemm,
                            hipFuncAttributeMaxDynamicSharedMemorySize, 135168);

  k_attn12<<<160, 192, 0, stream>>>(x, U1a, U3a, U2a, U1b, U3b, U2b,
                                    partAa, partAb, partMa, partMb, PB);
  k_attn3<<<1, 192, 0, stream>>>(partAa, partAb, partMa, partMb, bea, Vea, beb, Veb, tAa, tAb);
  k_node<<<625, 384, 0, stream>>>(x, tAa, tAb, w1, b1, w2, b2, hw, hb, outF, PB);
  k_gemm<<<40 * NC, 512, 135168, stream>>>(adj, PB, partC, S);
  k_epi<<<625, 192, 0, stream>>>(partC, outH, NC);
}

// Round 14
// 224.544 us; speedup vs baseline: 1.0796x; 1.0796x over previous
//
#include <hip/hip_runtime.h>
#include <hip/hip_bf16.h>
#include <math.h>

#define NN 10000

typedef __attribute__((ext_vector_type(4))) float f32x4;
typedef __attribute__((ext_vector_type(8))) short short8v;

__device__ __forceinline__ short f2bf(float f) {
  union { float f; unsigned u; } v; v.f = f;
  unsigned u = v.u + 0x7FFFu + ((v.u >> 16) & 1u);  // RNE
  return (short)(u >> 16);
}
__device__ __forceinline__ float bf2f(unsigned short h) {
  union { unsigned u; float f; } v; v.u = ((unsigned)h) << 16;
  return v.f;
}
__device__ __forceinline__ float artanh_(float xx) {
  xx = fminf(fmaxf(xx, -1.f + 1e-7f), 1.f - 1e-7f);
  return atanhf(xx);
}
__device__ __forceinline__ void proj16(float* v) {
  float s = 0.f;
#pragma unroll
  for (int i = 0; i < 16; ++i) s += v[i] * v[i];
  float n = fmaxf(sqrtf(s), 1e-15f);
  const float mxn = 1.0f - 4e-3f;
  if (n > mxn) {
    float sc = mxn / n;
#pragma unroll
    for (int i = 0; i < 16; ++i) v[i] *= sc;
  }
}
__device__ __forceinline__ short8v cvt8(const float4& u, const float4& w) {
  union { __hip_bfloat162 h; unsigned u32; } c0, c1, c2, c3;
  c0.h = __float22bfloat162_rn(make_float2(u.x, u.y));
  c1.h = __float22bfloat162_rn(make_float2(u.z, u.w));
  c2.h = __float22bfloat162_rn(make_float2(w.x, w.y));
  c3.h = __float22bfloat162_rn(make_float2(w.z, w.w));
  union { unsigned v[4]; short8v s; } r;
  r.v[0] = c0.u32; r.v[1] = c1.u32; r.v[2] = c2.u32; r.v[3] = c3.u32;
  return r.s;
}

// ---------------- K1: pass over x -> rhs (both branches) + partial a; zero step-312 PB tail ----------------
__global__ __launch_bounds__(192) void k_attn1(
    const float* __restrict__ x,
    const float* __restrict__ U1a, const float* __restrict__ U3a,
    const float* __restrict__ U1b, const float* __restrict__ U3b,
    float* __restrict__ rhsA, float* __restrict__ rhsB,
    float* __restrict__ partAa, float* __restrict__ partAb,
    unsigned short* __restrict__ PB) {
  __shared__ float xs[16 * 193];
  int tid = threadIdx.x;
  int f_ = tid / 12, t_ = tid - f_ * 12;
  int s_ = tid >> 4, nl_ = tid & 15;
  // zero PB pad: frag-step 312, shorts [256,512) of each of its 12 frags (k >= 10000)
  if (blockIdx.x == 79) {
    for (int i = tid; i < 3072; i += 192) {
      int tt = i >> 8, q = i & 255;
      PB[(size_t)(312 * 12 + tt) * 512 + 256 + q] = 0;
    }
  }
  float paa = 0.f, pab = 0.f;
  for (int tb = blockIdx.x; tb < 625; tb += 160) {
    int n0 = tb * 16;
    for (int i = tid; i < 16 * 192; i += 192) {
      int a = i / 192, j = i - a * 192;
      xs[a * 193 + j] = x[(size_t)(n0 + a) * 192 + j];
    }
    __syncthreads();
    float ra = 0.f, rb = 0.f;
#pragma unroll
    for (int f = 0; f < 16; ++f) {
      float xv = xs[nl_ * 193 + f * 12 + s_];
      ra += xv * U3a[f];
      rb += xv * U3b[f];
    }
    rhsA[s_ * NN + n0 + nl_] = ra;
    rhsB[s_ * NN + n0 + nl_] = rb;
#pragma unroll
    for (int nl = 0; nl < 16; ++nl) {
      float xv = xs[nl * 193 + f_ * 12 + t_];
      paa += xv * U1a[n0 + nl];
      pab += xv * U1b[n0 + nl];
    }
    __syncthreads();
  }
  partAa[blockIdx.x * 192 + tid] = paa;
  partAb[blockIdx.x * 192 + tid] = pab;
}

// ---------------- K2: M[f,s] partials ----------------
__global__ __launch_bounds__(192) void k_attn2(
    const float* __restrict__ U2a, const float* __restrict__ U2b,
    const float* __restrict__ rhsA, const float* __restrict__ rhsB,
    float* __restrict__ partMa, float* __restrict__ partMb) {
  int tid = threadIdx.x;
  int f = tid / 12, s = tid - f * 12;
  int nA = blockIdx.x * 125, nE = nA + 125;
  float ma = 0.f, mb = 0.f;
  for (int n = nA; n < nE; ++n) {
    ma += U2a[f * NN + n] * rhsA[s * NN + n];
    mb += U2b[f * NN + n] * rhsB[s * NN + n];
  }
  partMa[blockIdx.x * 192 + tid] = ma;
  partMb[blockIdx.x * 192 + tid] = mb;
}

// ---------------- K3: reduce partials, product, E, softmax -> tA (both) ----------------
__global__ __launch_bounds__(192) void k_attn3(
    const float* __restrict__ partAa, const float* __restrict__ partAb,
    const float* __restrict__ partMa, const float* __restrict__ partMb,
    const float* __restrict__ beA, const float* __restrict__ VeA,
    const float* __restrict__ beB, const float* __restrict__ VeB,
    float* __restrict__ tAa, float* __restrict__ tAb) {
  __shared__ float aa[192], ab[192], Ma[192], Mb[192];
  __shared__ float spA[144], spB[144], EA[144], EB[144];
  int tid = threadIdx.x;
  float s1 = 0.f, s2 = 0.f, s3 = 0.f, s4 = 0.f;
  for (int b = 0; b < 160; ++b) { s1 += partAa[b * 192 + tid]; s2 += partAb[b * 192 + tid]; }
  for (int b = 0; b < 80; ++b) { s3 += partMa[b * 192 + tid]; s4 += partMb[b * 192 + tid]; }
  aa[tid] = s1; ab[tid] = s2; Ma[tid] = s3; Mb[tid] = s4;
  __syncthreads();
  if (tid < 144) {
    int j = tid / 12, s = tid - j * 12;
    float pa = 0.f, pb = 0.f;
#pragma unroll
    for (int f = 0; f < 16; ++f) {
      pa += aa[f * 12 + j] * Ma[f * 12 + s];
      pb += ab[f * 12 + j] * Mb[f * 12 + s];
    }
    spA[tid] = 1.f / (1.f + expf(-(pa + beA[tid])));
    spB[tid] = 1.f / (1.f + expf(-(pb + beB[tid])));
  }
  __syncthreads();
  if (tid < 144) {
    int i = tid / 12, s = tid - i * 12;
    float ea = 0.f, eb = 0.f;
#pragma unroll
    for (int j = 0; j < 12; ++j) {
      ea += VeA[i * 12 + j] * spA[j * 12 + s];
      eb += VeB[i * 12 + j] * spB[j * 12 + s];
    }
    EA[tid] = ea; EB[tid] = eb;
  }
  __syncthreads();
  if (tid < 144) {
    int s = tid % 12;
    float ma = -1e30f, mb = -1e30f;
#pragma unroll
    for (int k = 0; k < 12; ++k) { ma = fmaxf(ma, EA[k * 12 + s]); mb = fmaxf(mb, EB[k * 12 + s]); }
    float da = 0.f, db = 0.f;
#pragma unroll
    for (int k = 0; k < 12; ++k) { da += expf(EA[k * 12 + s] - ma); db += expf(EB[k * 12 + s] - mb); }
    tAa[tid] = expf(EA[tid] - ma) / da;
    tAb[tid] = expf(EB[tid] - mb) / db;
  }
}

// ---------------- K4: per-node x_tat + conv (both) + hyperbolic -> PB (lane-ordered B frags), outF ----------------
__global__ __launch_bounds__(192) void k_node(
    const float* __restrict__ x,
    const float* __restrict__ tAa_g, const float* __restrict__ tAb_g,
    const float* __restrict__ w1g, const float* __restrict__ b1g,
    const float* __restrict__ w2g, const float* __restrict__ b2g,
    const float* __restrict__ hwg, const float* __restrict__ hbg,
    float* __restrict__ outF, unsigned short* __restrict__ PB) {
  __shared__ float xs[16 * 193], tbuf[16 * 193];
  __shared__ float tAa[144], tAb[144], w1[768], w2[768];
  __shared__ float cb1[16], cb2[16], hw[256], hbr[16];
  int tid = threadIdx.x;
  int nl = tid & 15, tt = tid >> 4;
  int n0 = blockIdx.x * 16;
  for (int i = tid; i < 144; i += 192) { tAa[i] = tAa_g[i]; tAb[i] = tAb_g[i]; }
  for (int i = tid; i < 768; i += 192) { w1[i] = w1g[i]; w2[i] = w2g[i]; }
  for (int i = tid; i < 256; i += 192) hw[i] = hwg[i];
  if (tid < 16) { cb1[tid] = b1g[tid]; cb2[tid] = b2g[tid]; hbr[tid] = hbg[tid]; }
  for (int i = tid; i < 16 * 192; i += 192) {
    int a = i / 192, j = i - a * 192;
    xs[a * 193 + j] = x[(size_t)(n0 + a) * 192 + j];
  }
  __syncthreads();

  float z[16];
  // ======== branch b (second attention -> conv2 -> final_output) ========
#pragma unroll
  for (int f = 0; f < 16; ++f) {
    float v = 0.f;
#pragma unroll
    for (int s = 0; s < 12; ++s) v += xs[nl * 193 + f * 12 + s] * tAb[s * 12 + tt];
    tbuf[nl * 193 + f * 12 + tt] = v;
  }
  __syncthreads();
#pragma unroll
  for (int o = 0; o < 16; ++o) z[o] = cb2[o];
#pragma unroll
  for (int k = 0; k < 3; ++k) {
    int t2 = tt + k - 1;
    if (t2 >= 0 && t2 < 12) {
#pragma unroll
      for (int i = 0; i < 16; ++i) {
        float xv = tbuf[nl * 193 + i * 12 + t2];
#pragma unroll
        for (int o = 0; o < 16; ++o) z[o] += xv * w2[o * 48 + i * 3 + k];
      }
    }
  }
  {
    float* op = outF + (size_t)tt * (NN * 16) + (size_t)(n0 + nl) * 16;
#pragma unroll
    for (int o = 0; o < 16; ++o) op[o] = z[o];
  }
  __syncthreads();

  // ======== branch a (first attention -> conv1 -> hyperbolic -> xt) ========
#pragma unroll
  for (int f = 0; f < 16; ++f) {
    float v = 0.f;
#pragma unroll
    for (int s = 0; s < 12; ++s) v += xs[nl * 193 + f * 12 + s] * tAa[s * 12 + tt];
    tbuf[nl * 193 + f * 12 + tt] = v;
  }
  __syncthreads();
#pragma unroll
  for (int o = 0; o < 16; ++o) z[o] = cb1[o];
#pragma unroll
  for (int k = 0; k < 3; ++k) {
    int t2 = tt + k - 1;
    if (t2 >= 0 && t2 < 12) {
#pragma unroll
      for (int i = 0; i < 16; ++i) {
        float xv = tbuf[nl * 193 + i * 12 + t2];
#pragma unroll
        for (int o = 0; o < 16; ++o) z[o] += xv * w1[o * 48 + i * 3 + k];
      }
    }
  }
  // x_hyp = proj(expmap0(z))
  float nz = 0.f;
#pragma unroll
  for (int i = 0; i < 16; ++i) nz += z[i] * z[i];
  nz = fmaxf(sqrtf(nz), 1e-15f);
  float sc0 = tanhf(nz) / nz;
#pragma unroll
  for (int i = 0; i < 16; ++i) z[i] *= sc0;
  proj16(z);
  // mobius_matvec(hgc_w, x_hyp)
  float xn = 0.f;
#pragma unroll
  for (int i = 0; i < 16; ++i) xn += z[i] * z[i];
  xn = fmaxf(sqrtf(xn), 1e-15f);
  float mx[16];
#pragma unroll
  for (int d = 0; d < 16; ++d) {
    float v = 0.f;
#pragma unroll
    for (int f = 0; f < 16; ++f) v += z[f] * hw[d * 16 + f];
    mx[d] = v;
  }
  float mxr = 0.f;
#pragma unroll
  for (int d = 0; d < 16; ++d) mxr += mx[d] * mx[d];
  mxr = sqrtf(mxr);
  float mxn = fmaxf(mxr, 1e-15f);
  float rs = tanhf(mxn / xn * artanh_(xn)) / mxn;
  if (mxr == 0.f) rs = 0.f;
#pragma unroll
  for (int d = 0; d < 16; ++d) mx[d] *= rs;
  proj16(mx);
  // hyp_b = proj(expmap0(hgc_b))
  float hb[16];
  float bn = 0.f;
#pragma unroll
  for (int i = 0; i < 16; ++i) { hb[i] = hbr[i]; bn += hb[i] * hb[i]; }
  bn = fmaxf(sqrtf(bn), 1e-15f);
  float sb = tanhf(bn) / bn;
#pragma unroll
  for (int i = 0; i < 16; ++i) hb[i] *= sb;
  proj16(hb);
  // res = proj(mobius_add(mx, hb))
  float x2 = 0.f, y2 = 0.f, xy = 0.f;
#pragma unroll
  for (int i = 0; i < 16; ++i) { x2 += mx[i] * mx[i]; y2 += hb[i] * hb[i]; xy += mx[i] * hb[i]; }
  float ca = 1.f + 2.f * xy + y2;
  float cbv = 1.f - x2;
  float den = fmaxf(1.f + 2.f * xy + x2 * y2, 1e-15f);
#pragma unroll
  for (int i = 0; i < 16; ++i) mx[i] = (ca * mx[i] + cbv * hb[i]) / den;
  proj16(mx);
  // xt = logmap0(res) -> PB in MFMA lane order:
  // PB[frag*512 + lane*8 + j] = B[k=(lane>>4)*8+j][col=lane&15]
  float pn = 0.f;
#pragma unroll
  for (int i = 0; i < 16; ++i) pn += mx[i] * mx[i];
  pn = fmaxf(sqrtf(pn), 1e-15f);
  float sl = artanh_(pn) / pn;
  {
    int nn2 = n0 + nl;
    int s = nn2 >> 5, c = nn2 & 31;
    unsigned short* pp = PB + (size_t)(s * 12 + tt) * 512 + (c >> 3) * 128 + (c & 7);
#pragma unroll
    for (int d = 0; d < 16; ++d)
      pp[d * 8] = (unsigned short)f2bf(mx[d] * sl);
  }
}

// ---------------- K5: sup = adj @ xt — BM=256, 8 waves, all-3-deep LDS, ONE barrier/step (R12) ----------------
__global__ __launch_bounds__(512) void k_gemm(
    const float* __restrict__ adj, const unsigned short* __restrict__ PB,
    unsigned short* __restrict__ partC, int S) {
  extern __shared__ char smem[];  // A: 3 x 32768 at p*32768 ; B: 3 x 12288 at 98304+p*12288
  int tid = threadIdx.x;
  int w = tid >> 6, lane = tid & 63;
  int bc = blockIdx.x / 40;
  int rt = blockIdx.x - bc * 40;
  int t0 = bc * S, t1 = min(313, t0 + S);
  int ns = t1 - t0;
  int r0 = lane & 15, kq = lane >> 4;
  int R0w = rt * 256 + w * 32;

  int aoffF = (((lane & 7) * 16) ^ ((lane >> 3) << 4)) >> 2;
  int arow[4];
#pragma unroll
  for (int i = 0; i < 4; ++i) arow[i] = min(R0w + i * 8 + (lane >> 3), NN - 1);

  int bc0 = w;
  int bc1 = (w < 4) ? (8 + w) : w;

  f32x4 acc0[12], acc1[12];
  f32x4 zz = {0.f, 0.f, 0.f, 0.f};
#pragma unroll
  for (int j = 0; j < 12; ++j) { acc0[j] = zz; acc1[j] = zz; }

  auto STAGE = [&](int p, int t) {  // exactly 6 gll per wave, all width-16
    char* Bdst = smem + 98304 + p * 12288;
    const char* Bsrc = (const char*)PB + (size_t)t * 12288;
    __builtin_amdgcn_global_load_lds((const void*)(Bsrc + bc0 * 1024 + lane * 16),
                                     (void*)(Bdst + bc0 * 1024 + lane * 16), 16, 0, 0);
    __builtin_amdgcn_global_load_lds((const void*)(Bsrc + bc1 * 1024 + lane * 16),
                                     (void*)(Bdst + bc1 * 1024 + lane * 16), 16, 0, 0);
    char* Adst = smem + p * 32768 + (w * 32) * 128;
#pragma unroll
    for (int i = 0; i < 4; ++i) {
      int fo = t * 32 + aoffF;
      if (fo >= NN) fo = 0;
      __builtin_amdgcn_global_load_lds((const void*)(adj + (size_t)arow[i] * NN + fo),
                                       (void*)(Adst + i * 1024 + lane * 16), 16, 0, 0);
    }
  };

  int xr = (r0 & 7) << 4;
  auto MM = [&](int p) {
    const char* Ab = smem + p * 32768 + (w * 32) * 128;
    const char* Bb = smem + 98304 + p * 12288;
    float4 a00 = *(const float4*)(Ab + r0 * 128 + ((kq * 32) ^ xr));
    float4 a01 = *(const float4*)(Ab + r0 * 128 + ((kq * 32 + 16) ^ xr));
    float4 a10 = *(const float4*)(Ab + (r0 + 16) * 128 + ((kq * 32) ^ xr));
    float4 a11 = *(const float4*)(Ab + (r0 + 16) * 128 + ((kq * 32 + 16) ^ xr));
    short8v fa0 = cvt8(a00, a01);
    short8v fa1 = cvt8(a10, a11);
#pragma unroll
    for (int j = 0; j < 12; ++j) {
      short8v b = *(const short8v*)(Bb + j * 1024 + lane * 16);
      acc0[j] = __builtin_amdgcn_mfma_f32_16x16x32_bf16(fa0, b, acc0[j], 0, 0, 0);
      acc1[j] = __builtin_amdgcn_mfma_f32_16x16x32_bf16(fa1, b, acc1[j], 0, 0, 0);
    }
  };

  STAGE(0, t0);
  if (ns > 1) STAGE(1, t0 + 1);
  if (ns > 1) asm volatile("s_waitcnt vmcnt(6)" ::: "memory");
  else        asm volatile("s_waitcnt vmcnt(0)" ::: "memory");
  __builtin_amdgcn_sched_barrier(0);
  __builtin_amdgcn_s_barrier();
  __builtin_amdgcn_sched_barrier(0);

  for (int i = 0; i < ns; ++i) {
    if (i + 2 < ns) STAGE((i + 2) % 3, t0 + i + 2);
    MM(i % 3);
    asm volatile("s_waitcnt lgkmcnt(0)" ::: "memory");
    if (i + 1 < ns) {
      if (i + 2 < ns) asm volatile("s_waitcnt vmcnt(6)" ::: "memory");
      else            asm volatile("s_waitcnt vmcnt(0)" ::: "memory");
      __builtin_amdgcn_sched_barrier(0);
      __builtin_amdgcn_s_barrier();
      __builtin_amdgcn_sched_barrier(0);
    }
  }

  size_t cbase = (size_t)bc * ((size_t)NN * 192);
  int drow = kq * 4;
#pragma unroll
  for (int j = 0; j < 12; ++j) {
#pragma unroll
    for (int r = 0; r < 4; ++r) {
      int rw0 = R0w + drow + r;
      int rw1 = R0w + 16 + drow + r;
      if (rw0 < NN)
        partC[cbase + (size_t)rw0 * 192 + j * 16 + r0] = (unsigned short)f2bf(acc0[j][r]);
      if (rw1 < NN)
        partC[cbase + (size_t)rw1 * 192 + j * 16 + r0] = (unsigned short)f2bf(acc1[j][r]);
    }
  }
}

// ---------------- K6: reduce partials + hyperbolic epilogue -> h (coalesced via LDS transpose) ----------------
__global__ __launch_bounds__(192) void k_epi(const unsigned short* __restrict__ partC,
                                             float* __restrict__ outH, int NC) {
  __shared__ float tr[16][196];
  int tid = threadIdx.x;
  int node = tid / 12, t = tid - node * 12;  // 16 nodes x 12 t per block
  int n = blockIdx.x * 16 + node;
  float sup[16];
#pragma unroll
  for (int d = 0; d < 16; ++d) sup[d] = 0.f;
  for (int c = 0; c < NC; ++c) {
    const short8v* p8 = (const short8v*)(partC + (size_t)c * (NN * 192) + (size_t)n * 192 + t * 16);
    short8v lo = p8[0], hi = p8[1];
#pragma unroll
    for (int d = 0; d < 8; ++d) sup[d] += bf2f((unsigned short)lo[d]);
#pragma unroll
    for (int d = 0; d < 8; ++d) sup[8 + d] += bf2f((unsigned short)hi[d]);
  }
  // agg = proj(expmap0(sup))
  float nn_ = 0.f;
#pragma unroll
  for (int d = 0; d < 16; ++d) nn_ += sup[d] * sup[d];
  nn_ = fmaxf(sqrtf(nn_), 1e-15f);
  float s0 = tanhf(nn_) / nn_;
#pragma unroll
  for (int d = 0; d < 16; ++d) sup[d] *= s0;
  proj16(sup);
  // relu(logmap0(agg))
  float pn = 0.f;
#pragma unroll
  for (int d = 0; d < 16; ++d) pn += sup[d] * sup[d];
  pn = fmaxf(sqrtf(pn), 1e-15f);
  float sl = artanh_(pn) / pn;
#pragma unroll
  for (int d = 0; d < 16; ++d) sup[d] = fmaxf(sup[d] * sl, 0.f);
  // proj(expmap0(...))
  float un = 0.f;
#pragma unroll
  for (int d = 0; d < 16; ++d) un += sup[d] * sup[d];
  un = fmaxf(sqrtf(un), 1e-15f);
  float se = tanhf(un) / un;
#pragma unroll
  for (int d = 0; d < 16; ++d) sup[d] *= se;
  proj16(sup);
  // stage h[node][d][t] into LDS, then write coalesced 16-float chunks
#pragma unroll
  for (int d = 0; d < 16; ++d) tr[node][d * 12 + t] = sup[d];
  __syncthreads();
  int wn = tid / 12, wc = tid - wn * 12;  // 16 nodes x 12 chunks of 16 floats
  float* hp = outH + (size_t)(blockIdx.x * 16 + wn) * 192 + wc * 16;
#pragma unroll
  for (int i = 0; i < 16; ++i) hp[i] = tr[wn][wc * 16 + i];
}

extern "C" void kernel_launch(void* const* d_in, const int* in_sizes, int n_in,
                              void* d_out, int out_size, void* d_ws, size_t ws_size,
                              hipStream_t stream) {
  const float* x   = (const float*)d_in[0];
  const float* adj = (const float*)d_in[1];
  const float* U1a = (const float*)d_in[2];
  const float* U2a = (const float*)d_in[3];
  const float* U3a = (const float*)d_in[4];
  const float* bea = (const float*)d_in[5];
  const float* Vea = (const float*)d_in[6];
  const float* U1b = (const float*)d_in[7];
  const float* U2b = (const float*)d_in[8];
  const float* U3b = (const float*)d_in[9];
  const float* beb = (const float*)d_in[10];
  const float* Veb = (const float*)d_in[11];
  const float* w1  = (const float*)d_in[12];
  const float* b1  = (const float*)d_in[13];
  const float* w2  = (const float*)d_in[14];
  const float* b2  = (const float*)d_in[15];
  const float* hw  = (const float*)d_in[16];
  const float* hb  = (const float*)d_in[17];
  float* outF = (float*)d_out;
  float* outH = (float*)d_out + 1920000;

  char* ws = (char*)d_ws;
  size_t off = 0;
  auto alloc = [&](size_t bytes) {
    char* p = ws + off;
    off = (off + bytes + 255) & ~(size_t)255;
    return p;
  };
  float* rhsA   = (float*)alloc((size_t)12 * NN * 4);
  float* rhsB   = (float*)alloc((size_t)12 * NN * 4);
  float* partAa = (float*)alloc(160 * 192 * 4);
  float* partAb = (float*)alloc(160 * 192 * 4);
  float* partMa = (float*)alloc(80 * 192 * 4);
  float* partMb = (float*)alloc(80 * 192 * 4);
  float* tAa    = (float*)alloc(144 * 4);
  float* tAb    = (float*)alloc(144 * 4);
  unsigned short* PB = (unsigned short*)alloc((size_t)314 * 6144 * 2);
  const int NC = 6;                 // 40 x 6 = 240 blocks -> single scheduling round
  unsigned short* partC = (unsigned short*)alloc((size_t)NC * NN * 192 * 2);
  (void)ws_size;
  int S = (313 + NC - 1) / NC;      // 53

  (void)hipFuncSetAttribute((const void*)k_gemm,
                            hipFuncAttributeMaxDynamicSharedMemorySize, 135168);

  k_attn1<<<160, 192, 0, stream>>>(x, U1a, U3a, U1b, U3b, rhsA, rhsB, partAa, partAb, PB);
  k_attn2<<<80, 192, 0, stream>>>(U2a, U2b, rhsA, rhsB, partMa, partMb);
  k_attn3<<<1, 192, 0, stream>>>(partAa, partAb, partMa, partMb, bea, Vea, beb, Veb, tAa, tAb);
  k_node<<<625, 192, 0, stream>>>(x, tAa, tAb, w1, b1, w2, b2, hw, hb, outF, PB);
  k_gemm<<<40 * NC, 512, 135168, stream>>>(adj, PB, partC, S);
  k_epi<<<625, 192, 0, stream>>>(partC, outH, NC);
}

// Round 15
// 214.403 us; speedup vs baseline: 1.1306x; 1.0473x over previous
//
#include <hip/hip_runtime.h>
#include <hip/hip_bf16.h>
#include <math.h>

#define NN 10000

typedef __attribute__((ext_vector_type(4))) float f32x4;
typedef __attribute__((ext_vector_type(8))) short short8v;

__device__ __forceinline__ short f2bf(float f) {
  union { float f; unsigned u; } v; v.f = f;
  unsigned u = v.u + 0x7FFFu + ((v.u >> 16) & 1u);  // RNE
  return (short)(u >> 16);
}
__device__ __forceinline__ float bf2f(unsigned short h) {
  union { unsigned u; float f; } v; v.u = ((unsigned)h) << 16;
  return v.f;
}
__device__ __forceinline__ float artanh_(float xx) {
  xx = fminf(fmaxf(xx, -1.f + 1e-7f), 1.f - 1e-7f);
  return atanhf(xx);
}
__device__ __forceinline__ void proj16(float* v) {
  float s = 0.f;
#pragma unroll
  for (int i = 0; i < 16; ++i) s += v[i] * v[i];
  float n = fmaxf(sqrtf(s), 1e-15f);
  const float mxn = 1.0f - 4e-3f;
  if (n > mxn) {
    float sc = mxn / n;
#pragma unroll
    for (int i = 0; i < 16; ++i) v[i] *= sc;
  }
}
__device__ __forceinline__ short8v cvt8(const float4& u, const float4& w) {
  union { __hip_bfloat162 h; unsigned u32; } c0, c1, c2, c3;
  c0.h = __float22bfloat162_rn(make_float2(u.x, u.y));
  c1.h = __float22bfloat162_rn(make_float2(u.z, u.w));
  c2.h = __float22bfloat162_rn(make_float2(w.x, w.y));
  c3.h = __float22bfloat162_rn(make_float2(w.z, w.w));
  union { unsigned v[4]; short8v s; } r;
  r.v[0] = c0.u32; r.v[1] = c1.u32; r.v[2] = c2.u32; r.v[3] = c3.u32;
  return r.s;
}

// ---------------- K1: pass over x -> rhs (both branches) + partial a; zero step-312 PB tail ----------------
__global__ __launch_bounds__(192) void k_attn1(
    const float* __restrict__ x,
    const float* __restrict__ U1a, const float* __restrict__ U3a,
    const float* __restrict__ U1b, const float* __restrict__ U3b,
    float* __restrict__ rhsA, float* __restrict__ rhsB,
    float* __restrict__ partAa, float* __restrict__ partAb,
    unsigned short* __restrict__ PB) {
  __shared__ float xs[16 * 193];
  int tid = threadIdx.x;
  int f_ = tid / 12, t_ = tid - f_ * 12;
  int s_ = tid >> 4, nl_ = tid & 15;
  // zero PB pad: frag-step 312, shorts [256,512) of each of its 12 frags (k >= 10000)
  if (blockIdx.x == 79) {
    for (int i = tid; i < 3072; i += 192) {
      int tt = i >> 8, q = i & 255;
      PB[(size_t)(312 * 12 + tt) * 512 + 256 + q] = 0;
    }
  }
  float paa = 0.f, pab = 0.f;
  for (int tb = blockIdx.x; tb < 625; tb += 160) {
    int n0 = tb * 16;
    for (int i = tid; i < 16 * 192; i += 192) {
      int a = i / 192, j = i - a * 192;
      xs[a * 193 + j] = x[(size_t)(n0 + a) * 192 + j];
    }
    __syncthreads();
    float ra = 0.f, rb = 0.f;
#pragma unroll
    for (int f = 0; f < 16; ++f) {
      float xv = xs[nl_ * 193 + f * 12 + s_];
      ra += xv * U3a[f];
      rb += xv * U3b[f];
    }
    rhsA[s_ * NN + n0 + nl_] = ra;
    rhsB[s_ * NN + n0 + nl_] = rb;
#pragma unroll
    for (int nl = 0; nl < 16; ++nl) {
      float xv = xs[nl * 193 + f_ * 12 + t_];
      paa += xv * U1a[n0 + nl];
      pab += xv * U1b[n0 + nl];
    }
    __syncthreads();
  }
  partAa[blockIdx.x * 192 + tid] = paa;
  partAb[blockIdx.x * 192 + tid] = pab;
}

// ---------------- K2: M[f,s] partials ----------------
__global__ __launch_bounds__(192) void k_attn2(
    const float* __restrict__ U2a, const float* __restrict__ U2b,
    const float* __restrict__ rhsA, const float* __restrict__ rhsB,
    float* __restrict__ partMa, float* __restrict__ partMb) {
  int tid = threadIdx.x;
  int f = tid / 12, s = tid - f * 12;
  int nA = blockIdx.x * 125, nE = nA + 125;
  float ma = 0.f, mb = 0.f;
  for (int n = nA; n < nE; ++n) {
    ma += U2a[f * NN + n] * rhsA[s * NN + n];
    mb += U2b[f * NN + n] * rhsB[s * NN + n];
  }
  partMa[blockIdx.x * 192 + tid] = ma;
  partMb[blockIdx.x * 192 + tid] = mb;
}

// ---------------- K3: reduce partials, product, E, softmax -> tA (both) ----------------
__global__ __launch_bounds__(192) void k_attn3(
    const float* __restrict__ partAa, const float* __restrict__ partAb,
    const float* __restrict__ partMa, const float* __restrict__ partMb,
    const float* __restrict__ beA, const float* __restrict__ VeA,
    const float* __restrict__ beB, const float* __restrict__ VeB,
    float* __restrict__ tAa, float* __restrict__ tAb) {
  __shared__ float aa[192], ab[192], Ma[192], Mb[192];
  __shared__ float spA[144], spB[144], EA[144], EB[144];
  int tid = threadIdx.x;
  float s1 = 0.f, s2 = 0.f, s3 = 0.f, s4 = 0.f;
  for (int b = 0; b < 160; ++b) { s1 += partAa[b * 192 + tid]; s2 += partAb[b * 192 + tid]; }
  for (int b = 0; b < 80; ++b) { s3 += partMa[b * 192 + tid]; s4 += partMb[b * 192 + tid]; }
  aa[tid] = s1; ab[tid] = s2; Ma[tid] = s3; Mb[tid] = s4;
  __syncthreads();
  if (tid < 144) {
    int j = tid / 12, s = tid - j * 12;
    float pa = 0.f, pb = 0.f;
#pragma unroll
    for (int f = 0; f < 16; ++f) {
      pa += aa[f * 12 + j] * Ma[f * 12 + s];
      pb += ab[f * 12 + j] * Mb[f * 12 + s];
    }
    spA[tid] = 1.f / (1.f + expf(-(pa + beA[tid])));
    spB[tid] = 1.f / (1.f + expf(-(pb + beB[tid])));
  }
  __syncthreads();
  if (tid < 144) {
    int i = tid / 12, s = tid - i * 12;
    float ea = 0.f, eb = 0.f;
#pragma unroll
    for (int j = 0; j < 12; ++j) {
      ea += VeA[i * 12 + j] * spA[j * 12 + s];
      eb += VeB[i * 12 + j] * spB[j * 12 + s];
    }
    EA[tid] = ea; EB[tid] = eb;
  }
  __syncthreads();
  if (tid < 144) {
    int s = tid % 12;
    float ma = -1e30f, mb = -1e30f;
#pragma unroll
    for (int k = 0; k < 12; ++k) { ma = fmaxf(ma, EA[k * 12 + s]); mb = fmaxf(mb, EB[k * 12 + s]); }
    float da = 0.f, db = 0.f;
#pragma unroll
    for (int k = 0; k < 12; ++k) { da += expf(EA[k * 12 + s] - ma); db += expf(EB[k * 12 + s] - mb); }
    tAa[tid] = expf(EA[tid] - ma) / da;
    tAb[tid] = expf(EB[tid] - mb) / db;
  }
}

// ---------------- K4: branch-split across blocks — blk<625: branch b -> outF ; blk>=625: branch a -> PB ----------------
__global__ __launch_bounds__(192) void k_node(
    const float* __restrict__ x,
    const float* __restrict__ tAa_g, const float* __restrict__ tAb_g,
    const float* __restrict__ w1g, const float* __restrict__ b1g,
    const float* __restrict__ w2g, const float* __restrict__ b2g,
    const float* __restrict__ hwg, const float* __restrict__ hbg,
    float* __restrict__ outF, unsigned short* __restrict__ PB) {
  __shared__ float xs[16 * 193], tbuf[16 * 193];
  __shared__ float tA[144], wv[768];
  __shared__ float cbv[16], hw[256], hbr[16];
  int tid = threadIdx.x;
  int nl = tid & 15, tt = tid >> 4;
  int isA = blockIdx.x >= 625;           // branch selector
  int n0 = (isA ? blockIdx.x - 625 : blockIdx.x) * 16;
  const float* tAg = isA ? tAa_g : tAb_g;
  const float* wg  = isA ? w1g : w2g;
  const float* bg  = isA ? b1g : b2g;
  for (int i = tid; i < 144; i += 192) tA[i] = tAg[i];
  for (int i = tid; i < 768; i += 192) wv[i] = wg[i];
  if (isA) for (int i = tid; i < 256; i += 192) hw[i] = hwg[i];
  if (tid < 16) { cbv[tid] = bg[tid]; if (isA) hbr[tid] = hbg[tid]; }
  for (int i = tid; i < 16 * 192; i += 192) {
    int a = i / 192, j = i - a * 192;
    xs[a * 193 + j] = x[(size_t)(n0 + a) * 192 + j];
  }
  __syncthreads();

  // x_tat for this branch
#pragma unroll
  for (int f = 0; f < 16; ++f) {
    float v = 0.f;
#pragma unroll
    for (int s = 0; s < 12; ++s) v += xs[nl * 193 + f * 12 + s] * tA[s * 12 + tt];
    tbuf[nl * 193 + f * 12 + tt] = v;
  }
  __syncthreads();

  // conv
  float z[16];
#pragma unroll
  for (int o = 0; o < 16; ++o) z[o] = cbv[o];
#pragma unroll
  for (int k = 0; k < 3; ++k) {
    int t2 = tt + k - 1;
    if (t2 >= 0 && t2 < 12) {
#pragma unroll
      for (int i = 0; i < 16; ++i) {
        float xv = tbuf[nl * 193 + i * 12 + t2];
#pragma unroll
        for (int o = 0; o < 16; ++o) z[o] += xv * wv[o * 48 + i * 3 + k];
      }
    }
  }

  if (!isA) {
    // branch b -> final_output
    float* op = outF + (size_t)tt * (NN * 16) + (size_t)(n0 + nl) * 16;
#pragma unroll
    for (int o = 0; o < 16; ++o) op[o] = z[o];
    return;
  }

  // branch a -> hyperbolic chain -> PB
  float nz = 0.f;
#pragma unroll
  for (int i = 0; i < 16; ++i) nz += z[i] * z[i];
  nz = fmaxf(sqrtf(nz), 1e-15f);
  float sc0 = tanhf(nz) / nz;
#pragma unroll
  for (int i = 0; i < 16; ++i) z[i] *= sc0;
  proj16(z);
  float xn = 0.f;
#pragma unroll
  for (int i = 0; i < 16; ++i) xn += z[i] * z[i];
  xn = fmaxf(sqrtf(xn), 1e-15f);
  float mx[16];
#pragma unroll
  for (int d = 0; d < 16; ++d) {
    float v = 0.f;
#pragma unroll
    for (int f = 0; f < 16; ++f) v += z[f] * hw[d * 16 + f];
    mx[d] = v;
  }
  float mxr = 0.f;
#pragma unroll
  for (int d = 0; d < 16; ++d) mxr += mx[d] * mx[d];
  mxr = sqrtf(mxr);
  float mxn = fmaxf(mxr, 1e-15f);
  float rs = tanhf(mxn / xn * artanh_(xn)) / mxn;
  if (mxr == 0.f) rs = 0.f;
#pragma unroll
  for (int d = 0; d < 16; ++d) mx[d] *= rs;
  proj16(mx);
  float hb[16];
  float bn = 0.f;
#pragma unroll
  for (int i = 0; i < 16; ++i) { hb[i] = hbr[i]; bn += hb[i] * hb[i]; }
  bn = fmaxf(sqrtf(bn), 1e-15f);
  float sb = tanhf(bn) / bn;
#pragma unroll
  for (int i = 0; i < 16; ++i) hb[i] *= sb;
  proj16(hb);
  float x2 = 0.f, y2 = 0.f, xy = 0.f;
#pragma unroll
  for (int i = 0; i < 16; ++i) { x2 += mx[i] * mx[i]; y2 += hb[i] * hb[i]; xy += mx[i] * hb[i]; }
  float ca = 1.f + 2.f * xy + y2;
  float cbf = 1.f - x2;
  float den = fmaxf(1.f + 2.f * xy + x2 * y2, 1e-15f);
#pragma unroll
  for (int i = 0; i < 16; ++i) mx[i] = (ca * mx[i] + cbf * hb[i]) / den;
  proj16(mx);
  float pn = 0.f;
#pragma unroll
  for (int i = 0; i < 16; ++i) pn += mx[i] * mx[i];
  pn = fmaxf(sqrtf(pn), 1e-15f);
  float sl = artanh_(pn) / pn;
  {
    int nn2 = n0 + nl;
    int s = nn2 >> 5, c = nn2 & 31;
    unsigned short* pp = PB + (size_t)(s * 12 + tt) * 512 + (c >> 3) * 128 + (c & 7);
#pragma unroll
    for (int d = 0; d < 16; ++d)
      pp[d * 8] = (unsigned short)f2bf(mx[d] * sl);
  }
}

// ---------------- K5: sup = adj @ xt — BM=256, 8 waves, all-3-deep LDS, ONE barrier/step (R12) ----------------
__global__ __launch_bounds__(512) void k_gemm(
    const float* __restrict__ adj, const unsigned short* __restrict__ PB,
    unsigned short* __restrict__ partC, int S) {
  extern __shared__ char smem[];  // A: 3 x 32768 at p*32768 ; B: 3 x 12288 at 98304+p*12288
  int tid = threadIdx.x;
  int w = tid >> 6, lane = tid & 63;
  int bc = blockIdx.x / 40;
  int rt = blockIdx.x - bc * 40;
  int t0 = bc * S, t1 = min(313, t0 + S);
  int ns = t1 - t0;
  int r0 = lane & 15, kq = lane >> 4;
  int R0w = rt * 256 + w * 32;

  int aoffF = (((lane & 7) * 16) ^ ((lane >> 3) << 4)) >> 2;
  int arow[4];
#pragma unroll
  for (int i = 0; i < 4; ++i) arow[i] = min(R0w + i * 8 + (lane >> 3), NN - 1);

  int bc0 = w;
  int bc1 = (w < 4) ? (8 + w) : w;

  f32x4 acc0[12], acc1[12];
  f32x4 zz = {0.f, 0.f, 0.f, 0.f};
#pragma unroll
  for (int j = 0; j < 12; ++j) { acc0[j] = zz; acc1[j] = zz; }

  auto STAGE = [&](int p, int t) {  // exactly 6 gll per wave, all width-16
    char* Bdst = smem + 98304 + p * 12288;
    const char* Bsrc = (const char*)PB + (size_t)t * 12288;
    __builtin_amdgcn_global_load_lds((const void*)(Bsrc + bc0 * 1024 + lane * 16),
                                     (void*)(Bdst + bc0 * 1024 + lane * 16), 16, 0, 0);
    __builtin_amdgcn_global_load_lds((const void*)(Bsrc + bc1 * 1024 + lane * 16),
                                     (void*)(Bdst + bc1 * 1024 + lane * 16), 16, 0, 0);
    char* Adst = smem + p * 32768 + (w * 32) * 128;
#pragma unroll
    for (int i = 0; i < 4; ++i) {
      int fo = t * 32 + aoffF;
      if (fo >= NN) fo = 0;
      __builtin_amdgcn_global_load_lds((const void*)(adj + (size_t)arow[i] * NN + fo),
                                       (void*)(Adst + i * 1024 + lane * 16), 16, 0, 0);
    }
  };

  int xr = (r0 & 7) << 4;
  auto MM = [&](int p) {
    const char* Ab = smem + p * 32768 + (w * 32) * 128;
    const char* Bb = smem + 98304 + p * 12288;
    float4 a00 = *(const float4*)(Ab + r0 * 128 + ((kq * 32) ^ xr));
    float4 a01 = *(const float4*)(Ab + r0 * 128 + ((kq * 32 + 16) ^ xr));
    float4 a10 = *(const float4*)(Ab + (r0 + 16) * 128 + ((kq * 32) ^ xr));
    float4 a11 = *(const float4*)(Ab + (r0 + 16) * 128 + ((kq * 32 + 16) ^ xr));
    short8v fa0 = cvt8(a00, a01);
    short8v fa1 = cvt8(a10, a11);
#pragma unroll
    for (int j = 0; j < 12; ++j) {
      short8v b = *(const short8v*)(Bb + j * 1024 + lane * 16);
      acc0[j] = __builtin_amdgcn_mfma_f32_16x16x32_bf16(fa0, b, acc0[j], 0, 0, 0);
      acc1[j] = __builtin_amdgcn_mfma_f32_16x16x32_bf16(fa1, b, acc1[j], 0, 0, 0);
    }
  };

  STAGE(0, t0);
  if (ns > 1) STAGE(1, t0 + 1);
  if (ns > 1) asm volatile("s_waitcnt vmcnt(6)" ::: "memory");
  else        asm volatile("s_waitcnt vmcnt(0)" ::: "memory");
  __builtin_amdgcn_sched_barrier(0);
  __builtin_amdgcn_s_barrier();
  __builtin_amdgcn_sched_barrier(0);

  for (int i = 0; i < ns; ++i) {
    if (i + 2 < ns) STAGE((i + 2) % 3, t0 + i + 2);
    MM(i % 3);
    asm volatile("s_waitcnt lgkmcnt(0)" ::: "memory");
    if (i + 1 < ns) {
      if (i + 2 < ns) asm volatile("s_waitcnt vmcnt(6)" ::: "memory");
      else            asm volatile("s_waitcnt vmcnt(0)" ::: "memory");
      __builtin_amdgcn_sched_barrier(0);
      __builtin_amdgcn_s_barrier();
      __builtin_amdgcn_sched_barrier(0);
    }
  }

  size_t cbase = (size_t)bc * ((size_t)NN * 192);
  int drow = kq * 4;
#pragma unroll
  for (int j = 0; j < 12; ++j) {
#pragma unroll
    for (int r = 0; r < 4; ++r) {
      int rw0 = R0w + drow + r;
      int rw1 = R0w + 16 + drow + r;
      if (rw0 < NN)
        partC[cbase + (size_t)rw0 * 192 + j * 16 + r0] = (unsigned short)f2bf(acc0[j][r]);
      if (rw1 < NN)
        partC[cbase + (size_t)rw1 * 192 + j * 16 + r0] = (unsigned short)f2bf(acc1[j][r]);
    }
  }
}

// ---------------- K6: reduce partials + hyperbolic epilogue -> h (coalesced via LDS transpose) ----------------
__global__ __launch_bounds__(192) void k_epi(const unsigned short* __restrict__ partC,
                                             float* __restrict__ outH, int NC) {
  __shared__ float tr[16][196];
  int tid = threadIdx.x;
  int node = tid / 12, t = tid - node * 12;  // 16 nodes x 12 t per block
  int n = blockIdx.x * 16 + node;
  float sup[16];
#pragma unroll
  for (int d = 0; d < 16; ++d) sup[d] = 0.f;
  for (int c = 0; c < NC; ++c) {
    const short8v* p8 = (const short8v*)(partC + (size_t)c * (NN * 192) + (size_t)n * 192 + t * 16);
    short8v lo = p8[0], hi = p8[1];
#pragma unroll
    for (int d = 0; d < 8; ++d) sup[d] += bf2f((unsigned short)lo[d]);
#pragma unroll
    for (int d = 0; d < 8; ++d) sup[8 + d] += bf2f((unsigned short)hi[d]);
  }
  // agg = proj(expmap0(sup))
  float nn_ = 0.f;
#pragma unroll
  for (int d = 0; d < 16; ++d) nn_ += sup[d] * sup[d];
  nn_ = fmaxf(sqrtf(nn_), 1e-15f);
  float s0 = tanhf(nn_) / nn_;
#pragma unroll
  for (int d = 0; d < 16; ++d) sup[d] *= s0;
  proj16(sup);
  // relu(logmap0(agg))
  float pn = 0.f;
#pragma unroll
  for (int d = 0; d < 16; ++d) pn += sup[d] * sup[d];
  pn = fmaxf(sqrtf(pn), 1e-15f);
  float sl = artanh_(pn) / pn;
#pragma unroll
  for (int d = 0; d < 16; ++d) sup[d] = fmaxf(sup[d] * sl, 0.f);
  // proj(expmap0(...))
  float un = 0.f;
#pragma unroll
  for (int d = 0; d < 16; ++d) un += sup[d] * sup[d];
  un = fmaxf(sqrtf(un), 1e-15f);
  float se = tanhf(un) / un;
#pragma unroll
  for (int d = 0; d < 16; ++d) sup[d] *= se;
  proj16(sup);
  // stage h[node][d][t] into LDS, then write coalesced 16-float chunks
#pragma unroll
  for (int d = 0; d < 16; ++d) tr[node][d * 12 + t] = sup[d];
  __syncthreads();
  int wn = tid / 12, wc = tid - wn * 12;  // 16 nodes x 12 chunks of 16 floats
  float* hp = outH + (size_t)(blockIdx.x * 16 + wn) * 192 + wc * 16;
#pragma unroll
  for (int i = 0; i < 16; ++i) hp[i] = tr[wn][wc * 16 + i];
}

extern "C" void kernel_launch(void* const* d_in, const int* in_sizes, int n_in,
                              void* d_out, int out_size, void* d_ws, size_t ws_size,
                              hipStream_t stream) {
  const float* x   = (const float*)d_in[0];
  const float* adj = (const float*)d_in[1];
  const float* U1a = (const float*)d_in[2];
  const float* U2a = (const float*)d_in[3];
  const float* U3a = (const float*)d_in[4];
  const float* bea = (const float*)d_in[5];
  const float* Vea = (const float*)d_in[6];
  const float* U1b = (const float*)d_in[7];
  const float* U2b = (const float*)d_in[8];
  const float* U3b = (const float*)d_in[9];
  const float* beb = (const float*)d_in[10];
  const float* Veb = (const float*)d_in[11];
  const float* w1  = (const float*)d_in[12];
  const float* b1  = (const float*)d_in[13];
  const float* w2  = (const float*)d_in[14];
  const float* b2  = (const float*)d_in[15];
  const float* hw  = (const float*)d_in[16];
  const float* hb  = (const float*)d_in[17];
  float* outF = (float*)d_out;
  float* outH = (float*)d_out + 1920000;

  char* ws = (char*)d_ws;
  size_t off = 0;
  auto alloc = [&](size_t bytes) {
    char* p = ws + off;
    off = (off + bytes + 255) & ~(size_t)255;
    return p;
  };
  float* rhsA   = (float*)alloc((size_t)12 * NN * 4);
  float* rhsB   = (float*)alloc((size_t)12 * NN * 4);
  float* partAa = (float*)alloc(160 * 192 * 4);
  float* partAb = (float*)alloc(160 * 192 * 4);
  float* partMa = (float*)alloc(80 * 192 * 4);
  float* partMb = (float*)alloc(80 * 192 * 4);
  float* tAa    = (float*)alloc(144 * 4);
  float* tAb    = (float*)alloc(144 * 4);
  unsigned short* PB = (unsigned short*)alloc((size_t)314 * 6144 * 2);
  const int NC = 6;                 // 40 x 6 = 240 blocks -> single scheduling round
  unsigned short* partC = (unsigned short*)alloc((size_t)NC * NN * 192 * 2);
  (void)ws_size;
  int S = (313 + NC - 1) / NC;      // 53

  (void)hipFuncSetAttribute((const void*)k_gemm,
                            hipFuncAttributeMaxDynamicSharedMemorySize, 135168);

  k_attn1<<<160, 192, 0, stream>>>(x, U1a, U3a, U1b, U3b, rhsA, rhsB, partAa, partAb, PB);
  k_attn2<<<80, 192, 0, stream>>>(U2a, U2b, rhsA, rhsB, partMa, partMb);
  k_attn3<<<1, 192, 0, stream>>>(partAa, partAb, partMa, partMb, bea, Vea, beb, Veb, tAa, tAb);
  k_node<<<1250, 192, 0, stream>>>(x, tAa, tAb, w1, b1, w2, b2, hw, hb, outF, PB);
  k_gemm<<<40 * NC, 512, 135168, stream>>>(adj, PB, partC, S);
  k_epi<<<625, 192, 0, stream>>>(partC, outH, NC);
}